// Round 8
// baseline (354.259 us; speedup 1.0000x reference)
//
#include <hip/hip_runtime.h>
#include <stdint.h>

// VectorQuantizer — bit-exact replication of the fp32 numpy reference.
//   d = sum(z*z,1)[:,None] + sum(c*c,1)[None,:] - 2.0*einsum('nc,kc->nk',z,c)
// sums: numpy pairwise_sum n=64 (8 accumulators + fixed tree). einsum: AVX512
// order — chained FMA depth 4 over blocks of 16, then reduce_add tree.
// Channel-pair packing on v_pk_fma_f32 / v_pk_add_f32 (bit-exact, rounds 6/7).
//
// Structure (round 8): no k-split. Block = 4 waves x 64 pts; each wave scans
// all 512 codes. Codebook staged in LDS in 4 phases of 128 rows (32 KB) ->
// hot loop is DS-only (in-order lgkmcnt, compiler pipelines), operands all
// VGPR. __launch_bounds__(256,2) gives a 256-reg budget so z stays in arch
// VGPRs (no AGPR parking -> no v_accvgpr_read copies). cnorm precomputed to
// d_ws by kernel 0 (identical pairwise formula).

#pragma clang fp contract(off)

#define KCODES 512
#define CDIM 64
#define HW 4096              // 64*64
#define ZQ_ELEMS 8388608     // 32*64*64*64

typedef float f2 __attribute__((ext_vector_type(2)));

static __device__ __forceinline__ f2 pk_fma(f2 a, f2 b, f2 c) {
    f2 d;
    asm("v_pk_fma_f32 %0, %1, %2, %3" : "=v"(d) : "v"(a), "v"(b), "v"(c));
    return d;
}
static __device__ __forceinline__ f2 pk_add(f2 a, f2 b) {
    f2 d;
    asm("v_pk_add_f32 %0, %1, %2" : "=v"(d) : "v"(a), "v"(b));
    return d;
}

// kernel 0: cnorm[k] = np.sum(cb*cb, axis=1) pairwise replica -> d_ws
__global__ __launch_bounds__(256) void vq_norms(const float* __restrict__ cb,
                                                float* __restrict__ cnorm_g)
{
    const int k = (int)blockIdx.x * 256 + (int)threadIdx.x;
    if (k >= KCODES) return;
    const float* row = cb + k * CDIM;
    float r[8];
    #pragma unroll
    for (int j = 0; j < 8; ++j) r[j] = row[j] * row[j];
    #pragma unroll
    for (int i = 8; i < 64; i += 8) {
        #pragma unroll
        for (int j = 0; j < 8; ++j) r[j] = r[j] + row[i + j] * row[i + j];
    }
    cnorm_g[k] = ((r[0] + r[1]) + (r[2] + r[3])) + ((r[4] + r[5]) + (r[6] + r[7]));
}

__global__ __launch_bounds__(256, 2) void vq_main(
    const float* __restrict__ z_e,
    const float* __restrict__ cb,
    const float* __restrict__ cnorm_g,
    float* __restrict__ out)
{
    __shared__ float rows[128 * CDIM];   // 32 KB: one 128-row phase
    __shared__ float cnorm_s[128];

    const int tid = (int)threadIdx.x;
    const int lane = tid & 63;
    const int w = __builtin_amdgcn_readfirstlane(tid >> 6);  // wave id 0..3

    // wave w owns 64 consecutive points
    const int n0 = (int)blockIdx.x * 256 + w * 64;
    const int b = n0 / HW;               // 256 | 4096 -> same b per block
    const int hw0 = n0 % HW;
    const float* zp = z_e + (size_t)b * CDIM * HW + hw0 + lane;

    // one point per lane; channel pairs packed: zz2[m] = {z[2m], z[2m+1]}
    f2 zz2[CDIM / 2];
    #pragma unroll
    for (int m = 0; m < CDIM / 2; ++m) {
        f2 t;
        t.x = zp[(size_t)(2 * m) * HW];
        t.y = zp[(size_t)(2 * m + 1) * HW];
        zz2[m] = t;
    }

    // np.sum(z*z, axis=1): pairwise replica (packed; per-scalar order exact)
    float sz;
    {
        f2 pr[4];
        #pragma unroll
        for (int t = 0; t < 4; ++t) pr[t] = zz2[t] * zz2[t];
        #pragma unroll
        for (int i = 8; i < 64; i += 8) {
            #pragma unroll
            for (int t = 0; t < 4; ++t) {
                f2 zt = zz2[(i + 2 * t) / 2];
                pr[t] = pr[t] + zt * zt;
            }
        }
        float s01 = pr[0].x + pr[0].y;
        float s23 = pr[1].x + pr[1].y;
        float s45 = pr[2].x + pr[2].y;
        float s67 = pr[3].x + pr[3].y;
        sz = (s01 + s23) + (s45 + s67);
    }

    f2 zero; zero.x = 0.f; zero.y = 0.f;

    float best = 3.4e38f;
    int bk = 0;

    for (int phase = 0; phase < 4; ++phase) {
        __syncthreads();
        // stage 128 rows (8192 floats) cooperatively: 8 float4 per thread
        {
            const float4* src = (const float4*)(cb + (size_t)phase * 128 * CDIM);
            float4* dst = (float4*)rows;
            #pragma unroll
            for (int i = 0; i < 8; ++i) dst[tid + 256 * i] = src[tid + 256 * i];
            if (tid < 128) cnorm_s[tid] = cnorm_g[phase * 128 + tid];
        }
        __syncthreads();

        for (int i = 0; i < 128; ++i) {
            const f2* cp = (const f2*)(rows + i * CDIM);  // wave-uniform LDS addr

            // einsum AVX512 order, packed chains pv[j] = {v[2j], v[2j+1]}:
            // v[l] = fma(z[l],c[l], fma(z[16+l],c[16+l], fma(z[32+l],c[32+l],
            //        fma(z[48+l],c[48+l], 0))))
            f2 pv[8];
            #pragma unroll
            for (int j = 0; j < 8; ++j) {
                f2 c0 = cp[j];
                f2 c1 = cp[8 + j];
                f2 c2 = cp[16 + j];
                f2 c3 = cp[24 + j];
                pv[j] = pk_fma(zz2[j], c0,
                          pk_fma(zz2[8 + j], c1,
                            pk_fma(zz2[16 + j], c2,
                              pk_fma(zz2[24 + j], c3, zero))));
            }
            // reduce_add tree (packed)
            f2 pe0 = pk_add(pv[0], pv[4]), pe1 = pk_add(pv[1], pv[5]);
            f2 pe2 = pk_add(pv[2], pv[6]), pe3 = pk_add(pv[3], pv[7]);
            f2 pf0 = pk_add(pe0, pe2), pf1 = pk_add(pe1, pe3);
            f2 pt = pk_add(pf0, pf1);              // {f0+f2, f1+f3}
            float dot = pt.x + pt.y;               // (f0+f2) + (f1+f3)

            float A = sz + cnorm_s[i];             // fl(sz + sc_k)
            float d = fmaf(dot, -2.f, A);          // fl(A - 2*dot); 2*dot exact

            const int k = phase * 128 + i;
            if (d < best) { best = d; bk = k; }    // strict <: first occurrence
        }
    }

    // indices (as float32, second output region)
    out[ZQ_ELEMS + n0 + lane] = (float)bk;

    // z_q gather: out[b][c][hw] = cb[bk][c]; coalesced 4B/lane stores
    const float* row = cb + (size_t)bk * CDIM;
    float* op = out + (size_t)b * CDIM * HW + hw0 + lane;
    #pragma unroll
    for (int c = 0; c < CDIM; ++c) {
        op[(size_t)c * HW] = row[c];
    }
}

extern "C" void kernel_launch(void* const* d_in, const int* in_sizes, int n_in,
                              void* d_out, int out_size, void* d_ws, size_t ws_size,
                              hipStream_t stream) {
    const float* z_e = (const float*)d_in[0];
    const float* cb  = (const float*)d_in[1];
    float* out = (float*)d_out;
    float* cnorm_g = (float*)d_ws;    // 512 floats
    vq_norms<<<dim3(2), dim3(256), 0, stream>>>(cb, cnorm_g);
    vq_main<<<dim3(512), dim3(256), 0, stream>>>(z_e, cb, cnorm_g, out);
}

// Round 10
// 350.344 us; speedup vs baseline: 1.0112x; 1.0112x over previous
//
#include <hip/hip_runtime.h>
#include <stdint.h>

// VectorQuantizer via MFMA screen + bit-exact fallback.
// Screen: S[k,n] = dot(cb_k, z_n) - |cb_k|^2/2 computed by
// mfma_f32_16x16x32_bf16 with z split to bf16 hi+lo (2 chained MFMAs share
// one accumulator), cb rounded to bf16. argmin_k d_np == argmax_k S up to a
// deviation bounded well below MARGIN_S. Points with a unique candidate
// (S >= max - MARGIN_S) take the screen answer; ambiguous points re-resolve
// with the PROVEN numpy-replica fp32 evaluation (rounds 3/7, absmax 0) over
// the gathered candidates, lex (d,k) = numpy first-occurrence.
// Layout: A = cb16 (M=codes), B = z (N=points). Wave = 16 points x 512 codes,
// 1-wave blocks, no LDS, no barriers. C/D: col(lane&15)=point,
// row((lane>>4)*4+reg)=code [m89-verified]; A/B frags: lane&15 = m/n,
// k = (lane>>4)*8 + j [m97/m120-verified].

#pragma clang fp contract(off)

#define KCODES 512
#define CDIM 64
#define HW 4096
#define ZQ_ELEMS 8388608
#define MARGIN_S 2e-4f     // S-margin = d-margin/2; realized deviation ~4e-5

typedef __attribute__((ext_vector_type(8))) short s8;
typedef __attribute__((ext_vector_type(4))) float fx4;

static __device__ __forceinline__ uint16_t bf16_rne(float f) {
    uint32_t u = __float_as_uint(f);
    return (uint16_t)((u + 0x7FFFu + ((u >> 16) & 1u)) >> 16);
}

// ---- proven numpy replicas (round 3/7, absmax 0) ----
static __device__ float sz_numpy(const float* zv) {
    float r[8];
    #pragma unroll
    for (int j = 0; j < 8; ++j) r[j] = zv[j] * zv[j];
    #pragma unroll
    for (int i = 8; i < 64; i += 8) {
        #pragma unroll
        for (int j = 0; j < 8; ++j) r[j] = r[j] + zv[i + j] * zv[i + j];
    }
    return ((r[0] + r[1]) + (r[2] + r[3])) + ((r[4] + r[5]) + (r[6] + r[7]));
}
static __device__ float d_numpy(const float* zv, const float* cb,
                                const float* cnorm_g, float sz, int k) {
    const float* ck = cb + k * CDIM;
    float v[16];
    #pragma unroll
    for (int l = 0; l < 16; ++l) {
        v[l] = fmaf(zv[l], ck[l],
                 fmaf(zv[16 + l], ck[16 + l],
                   fmaf(zv[32 + l], ck[32 + l],
                     fmaf(zv[48 + l], ck[48 + l], 0.f))));
    }
    float e0 = v[0] + v[8],  e1 = v[1] + v[9],  e2 = v[2] + v[10], e3 = v[3] + v[11];
    float e4 = v[4] + v[12], e5 = v[5] + v[13], e6 = v[6] + v[14], e7 = v[7] + v[15];
    float f0 = e0 + e4, f1 = e1 + e5, f2 = e2 + e6, f3 = e3 + e7;
    float dot = (f0 + f2) + (f1 + f3);
    float A = sz + cnorm_g[k];
    return fmaf(dot, -2.f, A);
}

// prep 1: exact cnorm (numpy pairwise replica)
__global__ __launch_bounds__(256) void vq_norms(const float* __restrict__ cb,
                                                float* __restrict__ cnorm_g)
{
    const int k = (int)blockIdx.x * 256 + (int)threadIdx.x;
    if (k >= KCODES) return;
    const float* row = cb + k * CDIM;
    float r[8];
    #pragma unroll
    for (int j = 0; j < 8; ++j) r[j] = row[j] * row[j];
    #pragma unroll
    for (int i = 8; i < 64; i += 8) {
        #pragma unroll
        for (int j = 0; j < 8; ++j) r[j] = r[j] + row[i + j] * row[i + j];
    }
    cnorm_g[k] = ((r[0] + r[1]) + (r[2] + r[3])) + ((r[4] + r[5]) + (r[6] + r[7]));
}

// prep 2: cb -> bf16 (RNE), element-parallel
__global__ __launch_bounds__(256) void vq_cvt(const float* __restrict__ cb,
                                              uint16_t* __restrict__ cb16)
{
    const int i = (int)blockIdx.x * 256 + (int)threadIdx.x;
    if (i < KCODES * CDIM) cb16[i] = bf16_rne(cb[i]);
}

__global__ __launch_bounds__(64, 2) void vq_main(
    const float* __restrict__ z_e,
    const float* __restrict__ cb,
    const float* __restrict__ cnorm_g,
    const uint16_t* __restrict__ cb16,
    float* __restrict__ out)
{
    const int tid = (int)threadIdx.x;          // 0..63, one wave
    const int p16 = tid & 15;                  // point within tile / n-index
    const int quad = tid >> 4;                 // 0..3
    const int quad4 = quad * 4;

    const int n = (int)blockIdx.x * 16 + p16;  // global point
    const int b = n >> 12;                     // n / 4096
    const int hwp = n & 4095;
    const float* zptr = z_e + (size_t)b * CDIM * HW + hwp;

    // B-frags: lane holds z[point=p16][ch = s*32 + quad*8 + j], split hi/lo bf16
    s8 bh[2], bl[2];
    #pragma unroll
    for (int s = 0; s < 2; ++s) {
        #pragma unroll
        for (int j = 0; j < 8; ++j) {
            const int ch = s * 32 + quad * 8 + j;
            float f = zptr[(size_t)ch * HW];
            uint16_t h = bf16_rne(f);
            float fh = __uint_as_float((uint32_t)h << 16);
            uint16_t l = bf16_rne(f - fh);
            bh[s][j] = (short)h;
            bl[s][j] = (short)l;
        }
    }

    // main: 32 M-frags x (2 ksteps x 2 splits) MFMAs; acc init = -cnorm/2
    fx4 accs[32];
    #pragma unroll 4
    for (int m = 0; m < 32; ++m) {
        fx4 cn = *(const fx4*)(cnorm_g + m * 16 + quad4);
        const uint16_t* ar = cb16 + (size_t)(m * 16 + p16) * CDIM + quad * 8;
        s8 a0 = *(const s8*)(ar);
        s8 a1 = *(const s8*)(ar + 32);
        fx4 acc = cn * -0.5f;
        acc = __builtin_amdgcn_mfma_f32_16x16x32_bf16(a0, bh[0], acc, 0, 0, 0);
        acc = __builtin_amdgcn_mfma_f32_16x16x32_bf16(a1, bh[1], acc, 0, 0, 0);
        acc = __builtin_amdgcn_mfma_f32_16x16x32_bf16(a0, bl[0], acc, 0, 0, 0);
        acc = __builtin_amdgcn_mfma_f32_16x16x32_bf16(a1, bl[1], acc, 0, 0, 0);
        accs[m] = acc;
    }

    // epilogue pass 1: per-point max S over 512 codes (4 lanes per point)
    float mx = -3.4e38f;
    #pragma unroll
    for (int m = 0; m < 32; ++m) {
        fx4 a = accs[m];
        mx = fmaxf(mx, fmaxf(fmaxf(a.x, a.y), fmaxf(a.z, a.w)));
    }
    mx = fmaxf(mx, __shfl_xor(mx, 16, 64));
    mx = fmaxf(mx, __shfl_xor(mx, 32, 64));
    const float T = mx - MARGIN_S;

    // pass 2: candidate bitmask (bit j=m*4+r <-> k = 16m + quad4 + r, ascending)
    uint32_t mk0 = 0, mk1 = 0, mk2 = 0, mk3 = 0;
    #pragma unroll
    for (int m = 0; m < 32; ++m) {
        fx4 a = accs[m];
        uint32_t w = (uint32_t)(a.x >= T) | ((uint32_t)(a.y >= T) << 1)
                   | ((uint32_t)(a.z >= T) << 2) | ((uint32_t)(a.w >= T) << 3);
        uint32_t sh = (uint32_t)(m & 7) * 4;
        if (m < 8)       mk0 |= w << sh;
        else if (m < 16) mk1 |= w << sh;
        else if (m < 24) mk2 |= w << sh;
        else             mk3 |= w << sh;
    }
    uint64_t lo = ((uint64_t)mk1 << 32) | mk0;
    uint64_t hi = ((uint64_t)mk3 << 32) | mk2;
    int cnt = __popcll(lo) + __popcll(hi);

    // first two candidate bits (ascending k within lane)
    uint64_t l2 = lo & (lo - 1);
    uint64_t h2 = lo ? hi : (hi & (hi - 1));
    int j1 = lo ? (__ffsll((long long)lo) - 1) : (hi ? 64 + __ffsll((long long)hi) - 1 : -1);
    int j2 = l2 ? (__ffsll((long long)l2) - 1) : (h2 ? 64 + __ffsll((long long)h2) - 1 : -1);
    int k1 = (j1 >= 0) ? (((j1 >> 2) << 4) + quad4 + (j1 & 3)) : 1023;
    int k2 = (j2 >= 0) ? (((j2 >> 2) << 4) + quad4 + (j2 & 3)) : 1023;

    // combine across the 4 lanes of this point
    int cnt_t = cnt + __shfl_xor(cnt, 16, 64);
    cnt_t += __shfl_xor(cnt_t, 32, 64);
    int kmin = min(k1, __shfl_xor(k1, 16, 64));
    kmin = min(kmin, __shfl_xor(kmin, 32, 64));
    int of = (cnt > 2) ? 1 : 0;
    of |= __shfl_xor(of, 16, 64);
    of |= __shfl_xor(of, 32, 64);

    // gather all candidate k's (uniform flow; valid = k<1023)
    int ka[8];
    #pragma unroll
    for (int g = 0; g < 4; ++g) {
        ka[2 * g]     = __shfl(k1, p16 + 16 * g, 64);
        ka[2 * g + 1] = __shfl(k2, p16 + 16 * g, 64);
    }

    int idx = kmin;  // unique-candidate fast path: provably the numpy argmin
    if (tid < 16 && cnt_t >= 2) {
        // exact numpy-replica resolution (rare)
        float zv[64];
        #pragma unroll
        for (int c = 0; c < 64; ++c) zv[c] = zptr[(size_t)c * HW];
        float sz = sz_numpy(zv);
        float bd = 3.4e38f; int bi = 1023;
        if (!of) {
            #pragma unroll
            for (int i = 0; i < 8; ++i) {
                int k = ka[i];
                if (k < 1023) {
                    float d = d_numpy(zv, cb, cnorm_g, sz, k);
                    if (d < bd || (d == bd && k < bi)) { bd = d; bi = k; }
                }
            }
        } else {
            for (int k = 0; k < KCODES; ++k) {
                float d = d_numpy(zv, cb, cnorm_g, sz, k);
                if (d < bd || (d == bd && k < bi)) { bd = d; bi = k; }
            }
        }
        idx = bi;
    }
    idx = __shfl(idx, p16, 64);   // broadcast owner's answer to the point group

    // outputs
    if (quad == 0) out[ZQ_ELEMS + n] = (float)idx;
    const float* crow = cb + (size_t)idx * CDIM;
    float* op = out + (size_t)b * CDIM * HW + hwp;
    #pragma unroll
    for (int c = 0; c < 16; ++c) {
        const int ch = quad * 16 + c;
        op[(size_t)ch * HW] = crow[ch];
    }
}

extern "C" void kernel_launch(void* const* d_in, const int* in_sizes, int n_in,
                              void* d_out, int out_size, void* d_ws, size_t ws_size,
                              hipStream_t stream) {
    const float* z_e = (const float*)d_in[0];
    const float* cb  = (const float*)d_in[1];
    float* out = (float*)d_out;
    float* cnorm_g = (float*)d_ws;                           // 2 KB
    uint16_t* cb16 = (uint16_t*)((char*)d_ws + 2048);        // 64 KB
    vq_norms<<<dim3(2),   dim3(256), 0, stream>>>(cb, cnorm_g);
    vq_cvt  <<<dim3(128), dim3(256), 0, stream>>>(cb, cb16);
    vq_main <<<dim3(8192), dim3(64), 0, stream>>>(z_e, cb, cnorm_g, cb16, out);
}

// Round 11
// 300.330 us; speedup vs baseline: 1.1796x; 1.1665x over previous
//
#include <hip/hip_runtime.h>
#include <stdint.h>

// VectorQuantizer: MFMA screen (32x32x16 bf16, 3 split-chains) + top-2 margin
// + bit-exact numpy-replica fallback kernel over compacted ambiguous points.
// Screen: S[k,n] = dot(cb_k, z_n) - |cb_k|^2/2 with cb ~ ch+cl, z ~ zh+zl
// (bf16 splits; chains hh, hl, lh; ll term negligible). Unique max within
// MARGIN_S (proven at 2e-4 in round 10) -> screen argmax is the numpy argmin.
// Ambiguous -> full 512-code exact replica per point (one wave each).

#pragma clang fp contract(off)

#define KCODES 512
#define CDIM 64
#define HW 4096
#define ZQ_ELEMS 8388608
#define MARGIN_S 2e-4f

// workspace layout (bytes)
#define WS_CNORM   0        // 512 f32 exact |c|^2 (numpy pairwise)
#define WS_CNORMH  2048     // 512 f32 = -|c|^2/2
#define WS_CH      4096     // 512*64 bf16 hi
#define WS_CL      69632    // 512*64 bf16 lo
#define WS_COUNT   135168   // int
#define WS_LIST    135172   // up to 131072 ints

typedef __attribute__((ext_vector_type(8)))  short s8;
typedef __attribute__((ext_vector_type(4)))  float fx4;
typedef __attribute__((ext_vector_type(16))) float fx16;

static __device__ __forceinline__ uint16_t bf16_rne(float f) {
    uint32_t u = __float_as_uint(f);
    return (uint16_t)((u + 0x7FFFu + ((u >> 16) & 1u)) >> 16);
}

// ---- proven numpy replicas (rounds 3/7/10, absmax 0) ----
static __device__ __forceinline__ float sz_numpy(const float* zv) {
    float r[8];
    #pragma unroll
    for (int j = 0; j < 8; ++j) r[j] = zv[j] * zv[j];
    #pragma unroll
    for (int i = 8; i < 64; i += 8) {
        #pragma unroll
        for (int j = 0; j < 8; ++j) r[j] = r[j] + zv[i + j] * zv[i + j];
    }
    return ((r[0] + r[1]) + (r[2] + r[3])) + ((r[4] + r[5]) + (r[6] + r[7]));
}
static __device__ __forceinline__ float d_numpy(const float* zv, const float* cb,
                                                const float* cnorm_g, float sz, int k) {
    const float* ck = cb + k * CDIM;
    float v[16];
    #pragma unroll
    for (int l = 0; l < 16; ++l) {
        v[l] = fmaf(zv[l], ck[l],
                 fmaf(zv[16 + l], ck[16 + l],
                   fmaf(zv[32 + l], ck[32 + l],
                     fmaf(zv[48 + l], ck[48 + l], 0.f))));
    }
    float e0 = v[0] + v[8],  e1 = v[1] + v[9],  e2 = v[2] + v[10], e3 = v[3] + v[11];
    float e4 = v[4] + v[12], e5 = v[5] + v[13], e6 = v[6] + v[14], e7 = v[7] + v[15];
    float f0 = e0 + e4, f1 = e1 + e5, f2 = e2 + e6, f3 = e3 + e7;
    float dot = (f0 + f2) + (f1 + f3);
    float A = sz + cnorm_g[k];
    return fmaf(dot, -2.f, A);
}

// prep 1: exact cnorm + (-cnorm/2)
__global__ __launch_bounds__(256) void vq_norms(const float* __restrict__ cb,
                                                float* __restrict__ cnorm_g,
                                                float* __restrict__ cnormh_g)
{
    const int k = (int)blockIdx.x * 256 + (int)threadIdx.x;
    if (k >= KCODES) return;
    const float* row = cb + k * CDIM;
    float r[8];
    #pragma unroll
    for (int j = 0; j < 8; ++j) r[j] = row[j] * row[j];
    #pragma unroll
    for (int i = 8; i < 64; i += 8) {
        #pragma unroll
        for (int j = 0; j < 8; ++j) r[j] = r[j] + row[i + j] * row[i + j];
    }
    float cn = ((r[0] + r[1]) + (r[2] + r[3])) + ((r[4] + r[5]) + (r[6] + r[7]));
    cnorm_g[k] = cn;
    cnormh_g[k] = -0.5f * cn;   // /2 exact
}

// prep 2: cb -> bf16 hi + lo residual
__global__ __launch_bounds__(256) void vq_cvt(const float* __restrict__ cb,
                                              uint16_t* __restrict__ ch16,
                                              uint16_t* __restrict__ cl16)
{
    const int i = (int)blockIdx.x * 256 + (int)threadIdx.x;
    if (i >= KCODES * CDIM) return;
    float c = cb[i];
    uint16_t hi = bf16_rne(c);
    ch16[i] = hi;
    cl16[i] = bf16_rne(c - __uint_as_float((uint32_t)hi << 16));
}

// main: 1 wave per 32 points; screen all 512 codes; top-2 streaming
__global__ __launch_bounds__(64, 4) void vq_main(
    const float* __restrict__ z_e,
    const float* __restrict__ cb,
    const float* __restrict__ cnormh_g,
    const uint16_t* __restrict__ ch16,
    const uint16_t* __restrict__ cl16,
    float* __restrict__ out,
    int* __restrict__ counter,
    int* __restrict__ list)
{
    const int lane = (int)threadIdx.x;     // 0..63
    const int p = lane & 31;               // point (B n-index) / code-in-tile (A m-index)
    const int h = lane >> 5;               // half: k-split of MFMA

    const int n = (int)blockIdx.x * 32 + p;
    const int b = n >> 12;
    const int hw = n & 4095;
    const float* zptr = z_e + (size_t)b * CDIM * HW + hw;

    // B-frags: point p, channel = s*16 + h*8 + j; split z = zh + zl (bf16)
    // loads: 32 lanes x consecutive hw -> full 128B lines, block-private
    s8 bh[4], bl[4];
    #pragma unroll
    for (int s = 0; s < 4; ++s) {
        #pragma unroll
        for (int j = 0; j < 8; ++j) {
            const int c = s * 16 + h * 8 + j;
            float f = zptr[(size_t)c * HW];
            uint16_t hi = bf16_rne(f);
            bh[s][j] = (short)hi;
            bl[s][j] = (short)bf16_rne(f - __uint_as_float((uint32_t)hi << 16));
        }
    }

    float max1 = -3.4e38f, max2 = -3.4e38f;
    int k1 = 0;

    #pragma unroll 2
    for (int t = 0; t < 16; ++t) {
        // A-frags: code row t*32+p, channel = s*16 + h*8 + j
        const uint16_t* arh = ch16 + (size_t)(t * 32 + p) * CDIM + h * 8;
        const uint16_t* arl = cl16 + (size_t)(t * 32 + p) * CDIM + h * 8;
        s8 ah[4], al[4];
        #pragma unroll
        for (int s = 0; s < 4; ++s) {
            ah[s] = *(const s8*)(arh + s * 16);
            al[s] = *(const s8*)(arl + s * 16);
        }

        // acc init = -|c_k|^2/2 at C/D cells: row(code) = (r&3)+8*(r>>2)+4h
        fx16 acc;
        #pragma unroll
        for (int q = 0; q < 4; ++q) {
            fx4 c4 = *(const fx4*)(cnormh_g + t * 32 + 4 * h + 8 * q);
            acc[q * 4 + 0] = c4.x; acc[q * 4 + 1] = c4.y;
            acc[q * 4 + 2] = c4.z; acc[q * 4 + 3] = c4.w;
        }

        // chains: hh, hl, lh (ll negligible vs margin)
        #pragma unroll
        for (int s = 0; s < 4; ++s)
            acc = __builtin_amdgcn_mfma_f32_32x32x16_bf16(ah[s], bh[s], acc, 0, 0, 0);
        #pragma unroll
        for (int s = 0; s < 4; ++s)
            acc = __builtin_amdgcn_mfma_f32_32x32x16_bf16(ah[s], bl[s], acc, 0, 0, 0);
        #pragma unroll
        for (int s = 0; s < 4; ++s)
            acc = __builtin_amdgcn_mfma_f32_32x32x16_bf16(al[s], bh[s], acc, 0, 0, 0);

        // streaming top-2 over this tile's 16 cells (ascending k)
        #pragma unroll
        for (int q = 0; q < 4; ++q) {
            #pragma unroll
            for (int i = 0; i < 4; ++i) {
                float sv = acc[q * 4 + i];
                const int kc = t * 32 + 8 * q + 4 * h + i;
                float losr = fminf(sv, max1);
                max2 = fmaxf(max2, losr);
                bool gt = sv > max1;
                k1 = gt ? kc : k1;
                max1 = fmaxf(sv, max1);
            }
        }
    }

    // merge the two k-halves of each point (lanes p and p+32)
    float m1o = __shfl_xor(max1, 32, 64);
    float m2o = __shfl_xor(max2, 32, 64);
    int   k1o = __shfl_xor(k1, 32, 64);
    float max2g = fmaxf(fminf(max1, m1o), fmaxf(max2, m2o));
    int   k1g = (m1o > max1) ? k1o : ((m1o == max1) ? min(k1, k1o) : k1);
    float max1g = fmaxf(max1, m1o);

    const bool amb = (max1g - max2g) < MARGIN_S;   // incl. exact ties
    if (amb && h == 0) {
        int pos = atomicAdd(counter, 1);
        list[pos] = n;
    }

    // outputs (ambiguous points overwritten by vq_fix)
    if (h == 0) out[ZQ_ELEMS + n] = (float)k1g;    // 32 consecutive = 128B line

    const float* crow = cb + (size_t)k1g * CDIM;
    float* op = out + (size_t)b * CDIM * HW + hw;
    #pragma unroll
    for (int c = 0; c < 32; ++c) {
        const int cc = h * 32 + c;
        op[(size_t)cc * HW] = crow[cc];            // 2x full 128B lines/instr
    }
}

// fallback: one wave per ambiguous point, full exact numpy scan
__global__ __launch_bounds__(256) void vq_fix(
    const float* __restrict__ z_e,
    const float* __restrict__ cb,
    const float* __restrict__ cnorm_g,
    const int* __restrict__ counter,
    const int* __restrict__ list,
    float* __restrict__ out)
{
    const int wv = (int)blockIdx.x * 4 + ((int)threadIdx.x >> 6);  // 1024 waves
    const int lane = (int)threadIdx.x & 63;
    const int count = *counter;

    for (int i = wv; i < count; i += 1024) {
        const int n = list[i];                      // wave-uniform
        const int b = n >> 12;
        const int hw = n & 4095;
        const float* zptr = z_e + (size_t)b * CDIM * HW + hw;

        float zv[64];                               // uniform -> scalar regs
        #pragma unroll
        for (int c = 0; c < 64; ++c) zv[c] = zptr[(size_t)c * HW];
        const float sz = sz_numpy(zv);

        float bd = 3.4e38f; int bi = 0x7fffffff;
        #pragma unroll
        for (int j = 0; j < 8; ++j) {
            const int k = lane + 64 * j;
            float d = d_numpy(zv, cb, cnorm_g, sz, k);
            if (d < bd || (d == bd && k < bi)) { bd = d; bi = k; }
        }
        // lex-min (d, k) across 64 lanes == numpy first-occurrence argmin
        #pragma unroll
        for (int off = 32; off; off >>= 1) {
            float d2 = __shfl_xor(bd, off, 64);
            int   k2 = __shfl_xor(bi, off, 64);
            if (d2 < bd || (d2 == bd && k2 < bi)) { bd = d2; bi = k2; }
        }

        if (lane == 0) out[ZQ_ELEMS + n] = (float)bi;
        const float* crow = cb + (size_t)bi * CDIM;
        float* op = out + (size_t)b * CDIM * HW + hw;
        op[(size_t)lane * HW] = crow[lane];         // lane = channel
    }
}

extern "C" void kernel_launch(void* const* d_in, const int* in_sizes, int n_in,
                              void* d_out, int out_size, void* d_ws, size_t ws_size,
                              hipStream_t stream) {
    const float* z_e = (const float*)d_in[0];
    const float* cb  = (const float*)d_in[1];
    float* out = (float*)d_out;

    float*    cnorm_g  = (float*)((char*)d_ws + WS_CNORM);
    float*    cnormh_g = (float*)((char*)d_ws + WS_CNORMH);
    uint16_t* ch16     = (uint16_t*)((char*)d_ws + WS_CH);
    uint16_t* cl16     = (uint16_t*)((char*)d_ws + WS_CL);
    int*      counter  = (int*)((char*)d_ws + WS_COUNT);
    int*      list     = (int*)((char*)d_ws + WS_LIST);

    hipMemsetAsync(counter, 0, sizeof(int), stream);
    vq_norms<<<dim3(2),   dim3(256), 0, stream>>>(cb, cnorm_g, cnormh_g);
    vq_cvt  <<<dim3(128), dim3(256), 0, stream>>>(cb, ch16, cl16);
    vq_main <<<dim3(4096), dim3(64), 0, stream>>>(z_e, cb, cnormh_g, ch16, cl16,
                                                  out, counter, list);
    vq_fix  <<<dim3(256), dim3(256), 0, stream>>>(z_e, cb, cnorm_g, counter, list, out);
}